// Round 10
// baseline (309.311 us; speedup 1.0000x reference)
//
#include <hip/hip_runtime.h>
#include <hip/hip_fp16.h>

// ---------------------------------------------------------------------------
// 3-layer GraphSAGE (DGL GraphConv norm='left'), N=100k, E=1M, D=H=O=64.
// Round 10 (structure = round 9):
//  * agg inner loop: wave-uniform width tiers (16-wide/4-deep -> 8-wide ->
//    4-wide -> predicated tail). cnt is per-wave uniform so all branches are
//    scalar; steady state has ZERO select/cndmask ops and no masked math
//    (round 9 paid ~60% wasted masked slots at mean degree 10).
//  * col[] stores pre-shifted BYTE offsets (node<<7) -> one less VALU op in
//    every gather address chain.
// ---------------------------------------------------------------------------

#define BSHIFT 10                 // 1024-node buckets
#define BMASK  ((1 << BSHIFT) - 1)
#define NBMAX  128                // max buckets (N <= 131072)
#define PCHUNK 2048               // edges per partition block
#define HCHUNK 4096               // edges per bucket-hist block

// chunked LDS histogram of edges into buckets (both directions)
__global__ __launch_bounds__(256) void bucket_hist_k(
    const int* __restrict__ src, const int* __restrict__ dst,
    int* __restrict__ bcnt_out, int* __restrict__ bcnt_in, int E) {
    __shared__ int h0[NBMAX], h1[NBMAX];
    const int t = threadIdx.x;
    const int e0 = blockIdx.x * HCHUNK;
    int n = E - e0; if (n > HCHUNK) n = HCHUNK;
    for (int i = t; i < NBMAX; i += 256) { h0[i] = 0; h1[i] = 0; }
    __syncthreads();
    for (int i = t; i < n; i += 256) {
        atomicAdd(&h0[src[e0 + i] >> BSHIFT], 1);
        atomicAdd(&h1[dst[e0 + i] >> BSHIFT], 1);
    }
    __syncthreads();
    if (t < NBMAX) {
        int c = h0[t];
        if (c) atomicAdd(&bcnt_out[t], c);
    } else {
        int b = t - NBMAX;
        int c = h1[b];
        if (c) atomicAdd(&bcnt_in[b], c);
    }
}

// r arrays from the degree arrays emitted by bucket_sort_k
__global__ void finalize_r_k(const int* __restrict__ deg_out, const int* __restrict__ deg_in,
                             float* __restrict__ r_out, float* __restrict__ r_in,
                             float* __restrict__ r_und, int N) {
    int t = blockIdx.x * blockDim.x + threadIdx.x;
    if (t < N) {
        int a = deg_out[t], b = deg_in[t];
        r_out[t] = 1.0f / (float)(a < 1 ? 1 : a);
        r_in[t]  = 1.0f / (float)(b < 1 ? 1 : b);
        int c = a + b;
        r_und[t] = 1.0f / (float)(c < 1 ? 1 : c);
    }
}

// single-block scan of bucket counts (NB <= 1024) -> bucket prefix + cursors
__global__ void bucket_scan_k(const int* __restrict__ bcnt_out, const int* __restrict__ bcnt_in,
                              int* __restrict__ bip_out, int* __restrict__ bip_in,
                              int* __restrict__ bcur_out, int* __restrict__ bcur_in, int NB) {
    __shared__ int s[1024];
    int t = threadIdx.x;
#pragma unroll 1
    for (int pass = 0; pass < 2; ++pass) {
        const int* bcnt = pass ? bcnt_in : bcnt_out;
        int* bip = pass ? bip_in : bip_out;
        int* bcur = pass ? bcur_in : bcur_out;
        int v = (t < NB) ? bcnt[t] : 0;
        s[t] = v; __syncthreads();
        for (int off = 1; off < 1024; off <<= 1) {
            int x = (t >= off) ? s[t - off] : 0;
            __syncthreads();
            s[t] += x;
            __syncthreads();
        }
        int excl = s[t] - v;
        if (t < NB) { bip[t] = excl; bcur[t] = excl; }
        if (t == NB) bip[NB] = excl;   // == E
        __syncthreads();
    }
}

// per-block run reservation partition: one contiguous run per (block,bucket),
// so every 64B line of part_* is written by a single XCD (except run edges).
// rec = (other_node << BSHIFT) | (local_node & BMASK)
__global__ __launch_bounds__(256) void partition_k(
    const int* __restrict__ src, const int* __restrict__ dst,
    int* __restrict__ bcur_out, int* __restrict__ bcur_in,
    unsigned* __restrict__ part_out, unsigned* __restrict__ part_in, int E) {
    __shared__ int sS[PCHUNK], sD[PCHUNK];
    __shared__ int hist[2][NBMAX];    // counts, then reused as local cursors
    __shared__ int gbase[2][NBMAX];
    const int t = threadIdx.x;
    const int e0 = blockIdx.x * PCHUNK;
    int n = E - e0; if (n > PCHUNK) n = PCHUNK;

    for (int i = t; i < NBMAX; i += 256) { hist[0][i] = 0; hist[1][i] = 0; }
    __syncthreads();
    for (int i = t; i < n; i += 256) {
        int s = src[e0 + i], d = dst[e0 + i];
        sS[i] = s; sD[i] = d;
        atomicAdd(&hist[0][d >> BSHIFT], 1);   // in-partition binned by dst
        atomicAdd(&hist[1][s >> BSHIFT], 1);   // out-partition binned by src
    }
    __syncthreads();
    if (t < NBMAX) {
        int c = hist[0][t];
        gbase[0][t] = c ? atomicAdd(&bcur_in[t], c) : 0;
        hist[0][t] = 0;
    } else {
        int b = t - NBMAX;
        int c = hist[1][b];
        gbase[1][b] = c ? atomicAdd(&bcur_out[b], c) : 0;
        hist[1][b] = 0;
    }
    __syncthreads();
    for (int i = t; i < n; i += 256) {
        int s = sS[i], d = sD[i];
        int bi = d >> BSHIFT;
        int p = gbase[0][bi] + atomicAdd(&hist[0][bi], 1);
        part_in[p] = ((unsigned)s << BSHIFT) | (unsigned)(d & BMASK);
        int bo = s >> BSHIFT;
        int q = gbase[1][bo] + atomicAdd(&hist[1][bo], 1);
        part_out[q] = ((unsigned)d << BSHIFT) | (unsigned)(s & BMASK);
    }
}

// one block per (bucket, direction): counting-sort the bucket's records by
// local node id (1024 bins). Emits CSR pointers ip[], degrees deg[], and
// col[] holding PRE-SHIFTED byte offsets (node << 7, fp16 row = 128B).
__global__ __launch_bounds__(256) void bucket_sort_k(
    const unsigned* __restrict__ pa, const int* __restrict__ bipa,
    const unsigned* __restrict__ pb, const int* __restrict__ bipb,
    int* __restrict__ ipa, int* __restrict__ ipb,
    int* __restrict__ cola, int* __restrict__ colb,
    int* __restrict__ dega, int* __restrict__ degb, int N, int E) {
    const unsigned* part = blockIdx.y ? pb : pa;
    const int* bip = blockIdx.y ? bipb : bipa;
    int* ip  = blockIdx.y ? ipb : ipa;
    int* col = blockIdx.y ? colb : cola;
    int* deg = blockIdx.y ? degb : dega;
    __shared__ int cnt[1024];
    __shared__ int ps[256];
    const int g = blockIdx.x, t = threadIdx.x;
    const int b = bip[g], e = bip[g + 1];

    for (int i = t; i < 1024; i += 256) cnt[i] = 0;
    __syncthreads();
    for (int i = b + t; i < e; i += 256) atomicAdd(&cnt[part[i] & (unsigned)BMASK], 1);
    __syncthreads();

    int c0 = cnt[4 * t + 0], c1 = cnt[4 * t + 1], c2 = cnt[4 * t + 2], c3 = cnt[4 * t + 3];
    int tot = c0 + c1 + c2 + c3;
    ps[t] = tot;
    __syncthreads();
    for (int off = 1; off < 256; off <<= 1) {
        int v = (t >= off) ? ps[t - off] : 0;
        __syncthreads();
        ps[t] += v;
        __syncthreads();
    }
    int base = b + ps[t] - tot;
    int node0 = (g << BSHIFT) + 4 * t;
    int cc[4] = {c0, c1, c2, c3};
#pragma unroll
    for (int j = 0; j < 4; ++j) {
        cnt[4 * t + j] = base;           // becomes the fill cursor
        int node = node0 + j;
        if (node < N) { ip[node] = base; deg[node] = cc[j]; }
        base += cc[j];
    }
    if (g == 0 && t == 0) ip[N] = E;
    __syncthreads();
    for (int i = b + t; i < e; i += 256) {
        unsigned rec = part[i];
        int p = atomicAdd(&cnt[rec & (unsigned)BMASK], 1);
        col[p] = (int)((rec >> BSHIFT) << 7);   // byte offset of fp16 row
    }
}

// hs[row] = fp16(in[row] * r[row]); each thread converts 4 features (8B store)
__global__ void scale_rows_k(const float* __restrict__ in, const float* __restrict__ r,
                             __half* __restrict__ out, int n4) {
    int t = blockIdx.x * blockDim.x + threadIdx.x;
    if (t < n4) {
        float s = r[t >> 4];
        float4 v = ((const float4*)in)[t];
        __half2 p01 = __floats2half2_rn(v.x * s, v.y * s);
        __half2 p23 = __floats2half2_rn(v.z * s, v.w * s);
        uint2 u;
        u.x = *(unsigned*)&p01;
        u.y = *(unsigned*)&p23;
        *(uint2*)(out + ((size_t)t << 2)) = u;
    }
}

// ---- aggregation: one wave per node, 16 lanes x 8B per fp16 row ----
__device__ __forceinline__ void acc_row(float4& acc, uint2 u) {
    __half2 h01 = *(__half2*)&u.x, h23 = *(__half2*)&u.y;
    acc.x += __low2float(h01); acc.y += __high2float(h01);
    acc.z += __low2float(h23); acc.w += __high2float(h23);
}

// Width-tiered inner loop: cnt is wave-uniform, so the tier branches are
// scalar. Steady state (full tiers) has no selects and no masked math.
__device__ __forceinline__ void agg_list(const char* __restrict__ hsb,
                                         const int* __restrict__ col,
                                         int b, int e, int lane, int grp, int fo8,
                                         float4& a0, float4& a1, float4& a2, float4& a3) {
    for (int base = b; base < e; base += 64) {
        int cnt = e - base; if (cnt > 64) cnt = 64;
        int my = (lane < cnt) ? col[base + lane] : 0;
        int j = 0;
        for (; j + 16 <= cnt; j += 16) {       // 4-deep, unconditional
            int o0 = __shfl(my, j + grp);
            int o1 = __shfl(my, j + 4 + grp);
            int o2 = __shfl(my, j + 8 + grp);
            int o3 = __shfl(my, j + 12 + grp);
            uint2 u0 = *(const uint2*)(hsb + o0 + fo8);
            uint2 u1 = *(const uint2*)(hsb + o1 + fo8);
            uint2 u2 = *(const uint2*)(hsb + o2 + fo8);
            uint2 u3 = *(const uint2*)(hsb + o3 + fo8);
            acc_row(a0, u0); acc_row(a1, u1); acc_row(a2, u2); acc_row(a3, u3);
        }
        if (j + 8 <= cnt) {                    // 2-deep, unconditional
            int o0 = __shfl(my, j + grp);
            int o1 = __shfl(my, j + 4 + grp);
            uint2 u0 = *(const uint2*)(hsb + o0 + fo8);
            uint2 u1 = *(const uint2*)(hsb + o1 + fo8);
            acc_row(a0, u0); acc_row(a1, u1);
            j += 8;
        }
        if (j + 4 <= cnt) {                    // 1 quad, unconditional
            int o0 = __shfl(my, j + grp);
            uint2 u0 = *(const uint2*)(hsb + o0 + fo8);
            acc_row(a0, u0);
            j += 4;
        }
        if (j < cnt) {                         // tail < 4, predicated
            int i0 = j + grp;
            int o0 = __shfl(my, i0 < cnt ? i0 : j);
            uint2 u0 = *(const uint2*)(hsb + o0 + fo8);
            if (i0 < cnt) acc_row(a0, u0);
        }
    }
}

__device__ __forceinline__ void agg_finish(float4 a0, float4 a1, float4 a2, float4 a3,
                                           float* __restrict__ agg, int node,
                                           int lane, int fo) {
    float4 acc;
    acc.x = (a0.x + a1.x) + (a2.x + a3.x);
    acc.y = (a0.y + a1.y) + (a2.y + a3.y);
    acc.z = (a0.z + a1.z) + (a2.z + a3.z);
    acc.w = (a0.w + a1.w) + (a2.w + a3.w);
    acc.x += __shfl_xor(acc.x, 16); acc.y += __shfl_xor(acc.y, 16);
    acc.z += __shfl_xor(acc.z, 16); acc.w += __shfl_xor(acc.w, 16);
    acc.x += __shfl_xor(acc.x, 32); acc.y += __shfl_xor(acc.y, 32);
    acc.z += __shfl_xor(acc.z, 32); acc.w += __shfl_xor(acc.w, 32);
    if (lane < 16) ((float4*)(agg + ((size_t)node << 6)))[fo] = acc;
}

__global__ void agg_k(const __half* __restrict__ hs, const int* __restrict__ ip,
                      const int* __restrict__ col, float* __restrict__ agg, int N) {
    int node = (blockIdx.x * blockDim.x + threadIdx.x) >> 6;
    int lane = threadIdx.x & 63;
    if (node >= N) return;
    const int grp = lane >> 4, fo = lane & 15, fo8 = fo << 3;
    float4 z = make_float4(0.f, 0.f, 0.f, 0.f);
    float4 a0 = z, a1 = z, a2 = z, a3 = z;
    agg_list((const char*)hs, col, ip[node], ip[node + 1], lane, grp, fo8, a0, a1, a2, a3);
    agg_finish(a0, a1, a2, a3, agg, node, lane, fo);
}

__global__ void agg_dual_k(const __half* __restrict__ hs,
                           const int* __restrict__ ipA, const int* __restrict__ colA,
                           const int* __restrict__ ipB, const int* __restrict__ colB,
                           float* __restrict__ agg, int N) {
    int node = (blockIdx.x * blockDim.x + threadIdx.x) >> 6;
    int lane = threadIdx.x & 63;
    if (node >= N) return;
    const int grp = lane >> 4, fo = lane & 15, fo8 = fo << 3;
    float4 z = make_float4(0.f, 0.f, 0.f, 0.f);
    float4 a0 = z, a1 = z, a2 = z, a3 = z;
    agg_list((const char*)hs, colA, ipA[node], ipA[node + 1], lane, grp, fo8, a0, a1, a2, a3);
    agg_list((const char*)hs, colB, ipB[node], ipB[node + 1], lane, grp, fo8, a0, a1, a2, a3);
    agg_finish(a0, a1, a2, a3, agg, node, lane, fo);
}

// out = [X, A] @ W + B (optional relu); optionally hs_out = fp16(out * rs[row])
// fused in the epilogue. 256 threads -> 64x64 tile, 4x4 per-thread, fp32.
// k-blocked x4: A-rows read as float4 (swizzle XOR is 8-granular so low 2 bits
// pass through), 4 W-rows per step -> 8 b128 LDS reads per 64 fma.
template <bool RELU, bool WRITE_HS>
__global__ __launch_bounds__(256, 2) void gemm_cat_k(
    const float* X, const float* A,
    const float* __restrict__ W, const float* __restrict__ B,
    const float* __restrict__ rs, __half* __restrict__ hs_out,
    float* out, int N) {
    __shared__ float sW[128 * 64];
    __shared__ float sX[64 * 64];
    __shared__ float sA[64 * 64];
    const int tid = threadIdx.x;

    for (int i = tid; i < 2048; i += 256) ((float4*)sW)[i] = ((const float4*)W)[i];

    const int row0 = blockIdx.x * 64;
    for (int i = tid; i < 1024; i += 256) {
        int r = i >> 4, c4 = (i & 15) << 2;
        int gr = row0 + r;
        float4 xv = make_float4(0.f, 0.f, 0.f, 0.f), av = xv;
        if (gr < N) {
            xv = ((const float4*)X)[(size_t)gr * 16 + (i & 15)];
            av = ((const float4*)A)[(size_t)gr * 16 + (i & 15)];
        }
        int sc = c4 ^ ((r & 12) << 1);
        *(float4*)&sX[(r << 6) + sc] = xv;
        *(float4*)&sA[(r << 6) + sc] = av;
    }
    __syncthreads();

    const int c0 = (tid & 15) << 2;
    const int r0 = (tid >> 4) << 2;
    const int sw = (r0 & 12) << 1;

    float4 bv = *(const float4*)(B + c0);
    float acc[4][4];
#pragma unroll
    for (int i = 0; i < 4; ++i) {
        acc[i][0] = bv.x; acc[i][1] = bv.y; acc[i][2] = bv.z; acc[i][3] = bv.w;
    }

#define GEMM_ROW(i, av)                                                       \
    acc[i][0] = fmaf(av.x, w0.x, acc[i][0]); acc[i][1] = fmaf(av.x, w0.y, acc[i][1]); \
    acc[i][2] = fmaf(av.x, w0.z, acc[i][2]); acc[i][3] = fmaf(av.x, w0.w, acc[i][3]); \
    acc[i][0] = fmaf(av.y, w1.x, acc[i][0]); acc[i][1] = fmaf(av.y, w1.y, acc[i][1]); \
    acc[i][2] = fmaf(av.y, w1.z, acc[i][2]); acc[i][3] = fmaf(av.y, w1.w, acc[i][3]); \
    acc[i][0] = fmaf(av.z, w2.x, acc[i][0]); acc[i][1] = fmaf(av.z, w2.y, acc[i][1]); \
    acc[i][2] = fmaf(av.z, w2.z, acc[i][2]); acc[i][3] = fmaf(av.z, w2.w, acc[i][3]); \
    acc[i][0] = fmaf(av.w, w3.x, acc[i][0]); acc[i][1] = fmaf(av.w, w3.y, acc[i][1]); \
    acc[i][2] = fmaf(av.w, w3.z, acc[i][2]); acc[i][3] = fmaf(av.w, w3.w, acc[i][3]);

#pragma unroll 4
    for (int kb = 0; kb < 64; kb += 4) {
        const int kx = kb ^ sw;
        float4 w0 = *(const float4*)&sW[((kb + 0) << 6) + c0];
        float4 w1 = *(const float4*)&sW[((kb + 1) << 6) + c0];
        float4 w2 = *(const float4*)&sW[((kb + 2) << 6) + c0];
        float4 w3 = *(const float4*)&sW[((kb + 3) << 6) + c0];
        float4 a0 = *(const float4*)&sX[((r0 + 0) << 6) + kx];
        float4 a1 = *(const float4*)&sX[((r0 + 1) << 6) + kx];
        float4 a2 = *(const float4*)&sX[((r0 + 2) << 6) + kx];
        float4 a3 = *(const float4*)&sX[((r0 + 3) << 6) + kx];
        GEMM_ROW(0, a0) GEMM_ROW(1, a1) GEMM_ROW(2, a2) GEMM_ROW(3, a3)
    }
#pragma unroll 4
    for (int kb = 0; kb < 64; kb += 4) {
        const int kx = kb ^ sw;
        float4 w0 = *(const float4*)&sW[((kb + 64) << 6) + c0];
        float4 w1 = *(const float4*)&sW[((kb + 65) << 6) + c0];
        float4 w2 = *(const float4*)&sW[((kb + 66) << 6) + c0];
        float4 w3 = *(const float4*)&sW[((kb + 67) << 6) + c0];
        float4 a0 = *(const float4*)&sA[((r0 + 0) << 6) + kx];
        float4 a1 = *(const float4*)&sA[((r0 + 1) << 6) + kx];
        float4 a2 = *(const float4*)&sA[((r0 + 2) << 6) + kx];
        float4 a3 = *(const float4*)&sA[((r0 + 3) << 6) + kx];
        GEMM_ROW(0, a0) GEMM_ROW(1, a1) GEMM_ROW(2, a2) GEMM_ROW(3, a3)
    }
#undef GEMM_ROW

#pragma unroll
    for (int i = 0; i < 4; ++i) {
        int gr = row0 + r0 + i;
        if (gr < N) {
            float4 o;
            o.x = RELU ? fmaxf(acc[i][0], 0.f) : acc[i][0];
            o.y = RELU ? fmaxf(acc[i][1], 0.f) : acc[i][1];
            o.z = RELU ? fmaxf(acc[i][2], 0.f) : acc[i][2];
            o.w = RELU ? fmaxf(acc[i][3], 0.f) : acc[i][3];
            *(float4*)(out + ((size_t)gr << 6) + c0) = o;
            if (WRITE_HS) {
                float rr = rs[gr];
                __half2 p01 = __floats2half2_rn(o.x * rr, o.y * rr);
                __half2 p23 = __floats2half2_rn(o.z * rr, o.w * rr);
                uint2 u;
                u.x = *(unsigned*)&p01;
                u.y = *(unsigned*)&p23;
                *(uint2*)(hs_out + ((size_t)gr << 6) + c0) = u;
            }
        }
    }
}

extern "C" void kernel_launch(void* const* d_in, const int* in_sizes, int n_in,
                              void* d_out, int out_size, void* d_ws, size_t ws_size,
                              hipStream_t stream) {
    const float* x  = (const float*)d_in[0];
    const int* src  = (const int*)d_in[1];
    const int* dst  = (const int*)d_in[2];
    const float* W1 = (const float*)d_in[3];
    const float* b1 = (const float*)d_in[4];
    const float* W2 = (const float*)d_in[5];
    const float* b2 = (const float*)d_in[6];
    const float* W3 = (const float*)d_in[7];
    const float* b3 = (const float*)d_in[8];

    const int N = in_sizes[0] / 64;
    const int E = in_sizes[1];
    const int NB = (N + BMASK) >> BSHIFT;   // 1024-node buckets (NB <= 128)

    // workspace layout
    float* bufH  = (float*)d_ws;                      // N*64 f32 hidden (h1, h2)
    __half* bufHS = (__half*)(bufH + (size_t)N * 64); // N*64 fp16 pre-scaled feats
    int* deg_out = (int*)(bufHS + (size_t)N * 64);    // N
    int* deg_in  = deg_out + N;                       // N
    float* r_out = (float*)(deg_in + N);              // N
    float* r_in  = r_out + N;                         // N
    float* r_und = r_in + N;                          // N
    int* ip_out  = (int*)(r_und + N);                 // N+1
    int* ip_in   = ip_out + (N + 1);                  // N+1
    int* bcnt_out = ip_in + (N + 1);                  // NB
    int* bcnt_in  = bcnt_out + NB;                    // NB
    int* bip_out  = bcnt_in + NB;                     // NB+1
    int* bip_in   = bip_out + (NB + 1);               // NB+1
    int* bcur_out = bip_in + (NB + 1);                // NB
    int* bcur_in  = bcur_out + NB;                    // NB
    unsigned* part_out = (unsigned*)(bcur_in + NB);   // E
    unsigned* part_in  = part_out + E;                // E
    int* col_out = (int*)(part_in + E);               // E
    int* col_in  = col_out + E;                       // E

    float* aggB = (float*)d_out;   // aggregate buffer doubles as output

    const int TPB = 256;
    const int gN  = (N + TPB - 1) / TPB;
    const int n4  = N * 16;
    const int g4  = (n4 + TPB - 1) / TPB;
    const int gAg = (int)(((size_t)N * 64 + TPB - 1) / TPB);
    const int gGm = (N + 63) / 64;
    const int gP  = (E + PCHUNK - 1) / PCHUNK;
    const int gH  = (E + HCHUNK - 1) / HCHUNK;

    // --- graph build: bucket hist -> scan -> run-reserved partition ->
    //     counting sort (emits CSR + degrees) -> r arrays ---
    hipMemsetAsync(bcnt_out, 0, 2 * (size_t)NB * sizeof(int), stream);
    bucket_hist_k<<<gH, TPB, 0, stream>>>(src, dst, bcnt_out, bcnt_in, E);
    bucket_scan_k<<<1, 1024, 0, stream>>>(bcnt_out, bcnt_in, bip_out, bip_in,
                                          bcur_out, bcur_in, NB);
    partition_k<<<gP, TPB, 0, stream>>>(src, dst, bcur_out, bcur_in,
                                        part_out, part_in, E);
    bucket_sort_k<<<dim3(NB, 2), TPB, 0, stream>>>(part_out, bip_out, part_in, bip_in,
                                                   ip_out, ip_in, col_out, col_in,
                                                   deg_out, deg_in, N, E);
    finalize_r_k<<<gN, TPB, 0, stream>>>(deg_out, deg_in, r_out, r_in, r_und, N);

    // --- layer 1: 'O' — agg over in-edges of hs0 = fp16(x * r_out) ---
    scale_rows_k<<<g4, TPB, 0, stream>>>(x, r_out, bufHS, n4);
    agg_k<<<gAg, TPB, 0, stream>>>(bufHS, ip_in, col_in, aggB, N);
    gemm_cat_k<true, true><<<gGm, TPB, 0, stream>>>(x, aggB, W1, b1, r_in, bufHS, bufH, N);

    // --- layer 2: 'I' — agg over out-edges of hs1 = fp16(h1 * r_in) ---
    agg_k<<<gAg, TPB, 0, stream>>>(bufHS, ip_out, col_out, aggB, N);
    gemm_cat_k<true, true><<<gGm, TPB, 0, stream>>>(bufH, aggB, W2, b2, r_und, bufHS, bufH, N);

    // --- layer 3: 'U' — agg both directions of hs2 = fp16(h2 * r_und) ---
    agg_dual_k<<<gAg, TPB, 0, stream>>>(bufHS, ip_in, col_in, ip_out, col_out, aggB, N);
    gemm_cat_k<false, false><<<gGm, TPB, 0, stream>>>(bufH, aggB, W3, b3, nullptr, nullptr,
                                                      (float*)d_out, N);
}

// Round 11
// 293.940 us; speedup vs baseline: 1.0523x; 1.0523x over previous
//
#include <hip/hip_runtime.h>
#include <hip/hip_fp16.h>

// ---------------------------------------------------------------------------
// 3-layer GraphSAGE (DGL GraphConv norm='left'), N=100k, E=1M, D=H=O=64.
// Round 11:
//  * agg inner loop reverted to round-9 depth-4 form (fastest measured: 53us)
//    + byte-offset col[] kept.
//  * bucket_sort_k: 256 -> 1024 threads/block (grid was 196 blocks on 256
//    CUs, <1 block/CU; the sort was build-phase's largest serial cost).
//  * finalize_r_k deleted: 1/max(deg,1) computed inline in scale_rows and
//    the GEMM epilogues from the deg arrays the sort already emits.
// Aggregation is at its structural floor: hs = 12.8MB > 4MB XCD L2, so ~40%
// of gathers miss to L3 (FETCH pinned at 103MB = 8 XCDs x 12.8MB).
// ---------------------------------------------------------------------------

#define BSHIFT 10                 // 1024-node buckets
#define BMASK  ((1 << BSHIFT) - 1)
#define NBMAX  128                // max buckets (N <= 131072)
#define PCHUNK 2048               // edges per partition block
#define HCHUNK 4096               // edges per bucket-hist block

// chunked LDS histogram of edges into buckets (both directions)
__global__ __launch_bounds__(256) void bucket_hist_k(
    const int* __restrict__ src, const int* __restrict__ dst,
    int* __restrict__ bcnt_out, int* __restrict__ bcnt_in, int E) {
    __shared__ int h0[NBMAX], h1[NBMAX];
    const int t = threadIdx.x;
    const int e0 = blockIdx.x * HCHUNK;
    int n = E - e0; if (n > HCHUNK) n = HCHUNK;
    for (int i = t; i < NBMAX; i += 256) { h0[i] = 0; h1[i] = 0; }
    __syncthreads();
    for (int i = t; i < n; i += 256) {
        atomicAdd(&h0[src[e0 + i] >> BSHIFT], 1);
        atomicAdd(&h1[dst[e0 + i] >> BSHIFT], 1);
    }
    __syncthreads();
    if (t < NBMAX) {
        int c = h0[t];
        if (c) atomicAdd(&bcnt_out[t], c);
    } else {
        int b = t - NBMAX;
        int c = h1[b];
        if (c) atomicAdd(&bcnt_in[b], c);
    }
}

// single-block scan of bucket counts (NB <= 1024) -> bucket prefix + cursors
__global__ void bucket_scan_k(const int* __restrict__ bcnt_out, const int* __restrict__ bcnt_in,
                              int* __restrict__ bip_out, int* __restrict__ bip_in,
                              int* __restrict__ bcur_out, int* __restrict__ bcur_in, int NB) {
    __shared__ int s[1024];
    int t = threadIdx.x;
#pragma unroll 1
    for (int pass = 0; pass < 2; ++pass) {
        const int* bcnt = pass ? bcnt_in : bcnt_out;
        int* bip = pass ? bip_in : bip_out;
        int* bcur = pass ? bcur_in : bcur_out;
        int v = (t < NB) ? bcnt[t] : 0;
        s[t] = v; __syncthreads();
        for (int off = 1; off < 1024; off <<= 1) {
            int x = (t >= off) ? s[t - off] : 0;
            __syncthreads();
            s[t] += x;
            __syncthreads();
        }
        int excl = s[t] - v;
        if (t < NB) { bip[t] = excl; bcur[t] = excl; }
        if (t == NB) bip[NB] = excl;   // == E
        __syncthreads();
    }
}

// per-block run reservation partition: one contiguous run per (block,bucket),
// so every 64B line of part_* is written by a single XCD (except run edges).
// rec = (other_node << BSHIFT) | (local_node & BMASK)
__global__ __launch_bounds__(256) void partition_k(
    const int* __restrict__ src, const int* __restrict__ dst,
    int* __restrict__ bcur_out, int* __restrict__ bcur_in,
    unsigned* __restrict__ part_out, unsigned* __restrict__ part_in, int E) {
    __shared__ int sS[PCHUNK], sD[PCHUNK];
    __shared__ int hist[2][NBMAX];    // counts, then reused as local cursors
    __shared__ int gbase[2][NBMAX];
    const int t = threadIdx.x;
    const int e0 = blockIdx.x * PCHUNK;
    int n = E - e0; if (n > PCHUNK) n = PCHUNK;

    for (int i = t; i < NBMAX; i += 256) { hist[0][i] = 0; hist[1][i] = 0; }
    __syncthreads();
    for (int i = t; i < n; i += 256) {
        int s = src[e0 + i], d = dst[e0 + i];
        sS[i] = s; sD[i] = d;
        atomicAdd(&hist[0][d >> BSHIFT], 1);   // in-partition binned by dst
        atomicAdd(&hist[1][s >> BSHIFT], 1);   // out-partition binned by src
    }
    __syncthreads();
    if (t < NBMAX) {
        int c = hist[0][t];
        gbase[0][t] = c ? atomicAdd(&bcur_in[t], c) : 0;
        hist[0][t] = 0;
    } else {
        int b = t - NBMAX;
        int c = hist[1][b];
        gbase[1][b] = c ? atomicAdd(&bcur_out[b], c) : 0;
        hist[1][b] = 0;
    }
    __syncthreads();
    for (int i = t; i < n; i += 256) {
        int s = sS[i], d = sD[i];
        int bi = d >> BSHIFT;
        int p = gbase[0][bi] + atomicAdd(&hist[0][bi], 1);
        part_in[p] = ((unsigned)s << BSHIFT) | (unsigned)(d & BMASK);
        int bo = s >> BSHIFT;
        int q = gbase[1][bo] + atomicAdd(&hist[1][bo], 1);
        part_out[q] = ((unsigned)d << BSHIFT) | (unsigned)(s & BMASK);
    }
}

// one 1024-thread block per (bucket, direction): counting-sort the bucket's
// records by local node id (1024 bins, 1 bin/thread). Emits CSR pointers
// ip[], degrees deg[], and col[] holding PRE-SHIFTED byte offsets (node<<7).
__global__ __launch_bounds__(1024) void bucket_sort_k(
    const unsigned* __restrict__ pa, const int* __restrict__ bipa,
    const unsigned* __restrict__ pb, const int* __restrict__ bipb,
    int* __restrict__ ipa, int* __restrict__ ipb,
    int* __restrict__ cola, int* __restrict__ colb,
    int* __restrict__ dega, int* __restrict__ degb, int N, int E) {
    const unsigned* part = blockIdx.y ? pb : pa;
    const int* bip = blockIdx.y ? bipb : bipa;
    int* ip  = blockIdx.y ? ipb : ipa;
    int* col = blockIdx.y ? colb : cola;
    int* deg = blockIdx.y ? degb : dega;
    __shared__ int cnt[1024];
    __shared__ int s[1024];
    const int g = blockIdx.x, t = threadIdx.x;
    const int b = bip[g], e = bip[g + 1];

    cnt[t] = 0;
    __syncthreads();
    for (int i = b + t; i < e; i += 1024) atomicAdd(&cnt[part[i] & (unsigned)BMASK], 1);
    __syncthreads();

    int v = cnt[t];
    s[t] = v;
    __syncthreads();
    for (int off = 1; off < 1024; off <<= 1) {
        int x = (t >= off) ? s[t - off] : 0;
        __syncthreads();
        s[t] += x;
        __syncthreads();
    }
    int base = b + s[t] - v;                  // exclusive prefix within bucket
    int node = (g << BSHIFT) + t;
    if (node < N) { ip[node] = base; deg[node] = v; }
    cnt[t] = base;                            // becomes the fill cursor
    if (g == 0 && t == 0) ip[N] = E;
    __syncthreads();
    for (int i = b + t; i < e; i += 1024) {
        unsigned rec = part[i];
        int p = atomicAdd(&cnt[rec & (unsigned)BMASK], 1);
        col[p] = (int)((rec >> BSHIFT) << 7); // byte offset of fp16 row
    }
}

// hs[row] = fp16(in[row] / max(deg[row],1)); 4 features per thread (8B store)
__global__ void scale_rows_k(const float* __restrict__ in, const int* __restrict__ deg,
                             __half* __restrict__ out, int n4) {
    int t = blockIdx.x * blockDim.x + threadIdx.x;
    if (t < n4) {
        int m = deg[t >> 4];
        float s = 1.0f / (float)(m < 1 ? 1 : m);
        float4 v = ((const float4*)in)[t];
        __half2 p01 = __floats2half2_rn(v.x * s, v.y * s);
        __half2 p23 = __floats2half2_rn(v.z * s, v.w * s);
        uint2 u;
        u.x = *(unsigned*)&p01;
        u.y = *(unsigned*)&p23;
        *(uint2*)(out + ((size_t)t << 2)) = u;
    }
}

// ---- aggregation: one wave per node, 16 lanes x 8B per fp16 row,
//      16 edges per inner iter, 4 rows in flight, 4 fp32 acc chains ----
__device__ __forceinline__ void acc_row(float4& acc, uint2 u) {
    __half2 h01 = *(__half2*)&u.x, h23 = *(__half2*)&u.y;
    acc.x += __low2float(h01); acc.y += __high2float(h01);
    acc.z += __low2float(h23); acc.w += __high2float(h23);
}

__device__ __forceinline__ void agg_list(const char* __restrict__ hsb,
                                         const int* __restrict__ col,
                                         int b, int e, int lane, int grp, int fo8,
                                         float4& a0, float4& a1, float4& a2, float4& a3) {
    for (int base = b; base < e; base += 64) {
        int cnt = e - base; if (cnt > 64) cnt = 64;
        int my = (lane < cnt) ? col[base + lane] : 0;
        for (int j = 0; j < cnt; j += 16) {
            int i0 = j + grp, i1 = j + 4 + grp, i2 = j + 8 + grp, i3 = j + 12 + grp;
            int o0 = __shfl(my, i0 < cnt ? i0 : 0);
            int o1 = __shfl(my, i1 < cnt ? i1 : 0);
            int o2 = __shfl(my, i2 < cnt ? i2 : 0);
            int o3 = __shfl(my, i3 < cnt ? i3 : 0);
            uint2 u0 = *(const uint2*)(hsb + o0 + fo8);
            uint2 u1 = *(const uint2*)(hsb + o1 + fo8);
            uint2 u2 = *(const uint2*)(hsb + o2 + fo8);
            uint2 u3 = *(const uint2*)(hsb + o3 + fo8);
            if (i0 < cnt) acc_row(a0, u0);
            if (i1 < cnt) acc_row(a1, u1);
            if (i2 < cnt) acc_row(a2, u2);
            if (i3 < cnt) acc_row(a3, u3);
        }
    }
}

__device__ __forceinline__ void agg_finish(float4 a0, float4 a1, float4 a2, float4 a3,
                                           float* __restrict__ agg, int node,
                                           int lane, int fo) {
    float4 acc;
    acc.x = (a0.x + a1.x) + (a2.x + a3.x);
    acc.y = (a0.y + a1.y) + (a2.y + a3.y);
    acc.z = (a0.z + a1.z) + (a2.z + a3.z);
    acc.w = (a0.w + a1.w) + (a2.w + a3.w);
    acc.x += __shfl_xor(acc.x, 16); acc.y += __shfl_xor(acc.y, 16);
    acc.z += __shfl_xor(acc.z, 16); acc.w += __shfl_xor(acc.w, 16);
    acc.x += __shfl_xor(acc.x, 32); acc.y += __shfl_xor(acc.y, 32);
    acc.z += __shfl_xor(acc.z, 32); acc.w += __shfl_xor(acc.w, 32);
    if (lane < 16) ((float4*)(agg + ((size_t)node << 6)))[fo] = acc;
}

__global__ void agg_k(const __half* __restrict__ hs, const int* __restrict__ ip,
                      const int* __restrict__ col, float* __restrict__ agg, int N) {
    int node = (blockIdx.x * blockDim.x + threadIdx.x) >> 6;
    int lane = threadIdx.x & 63;
    if (node >= N) return;
    const int grp = lane >> 4, fo = lane & 15, fo8 = fo << 3;
    float4 z = make_float4(0.f, 0.f, 0.f, 0.f);
    float4 a0 = z, a1 = z, a2 = z, a3 = z;
    agg_list((const char*)hs, col, ip[node], ip[node + 1], lane, grp, fo8, a0, a1, a2, a3);
    agg_finish(a0, a1, a2, a3, agg, node, lane, fo);
}

__global__ void agg_dual_k(const __half* __restrict__ hs,
                           const int* __restrict__ ipA, const int* __restrict__ colA,
                           const int* __restrict__ ipB, const int* __restrict__ colB,
                           float* __restrict__ agg, int N) {
    int node = (blockIdx.x * blockDim.x + threadIdx.x) >> 6;
    int lane = threadIdx.x & 63;
    if (node >= N) return;
    const int grp = lane >> 4, fo = lane & 15, fo8 = fo << 3;
    float4 z = make_float4(0.f, 0.f, 0.f, 0.f);
    float4 a0 = z, a1 = z, a2 = z, a3 = z;
    agg_list((const char*)hs, colA, ipA[node], ipA[node + 1], lane, grp, fo8, a0, a1, a2, a3);
    agg_list((const char*)hs, colB, ipB[node], ipB[node + 1], lane, grp, fo8, a0, a1, a2, a3);
    agg_finish(a0, a1, a2, a3, agg, node, lane, fo);
}

// out = [X, A] @ W + B (optional relu); optionally hs_out = fp16(out / deg)
// with deg = dga[row] (+ dgb[row] if DEG2), clamped min 1, fused in epilogue.
// 256 threads -> 64x64 tile, 4x4 per-thread, fp32. k-blocked x4.
template <bool RELU, bool WRITE_HS, bool DEG2>
__global__ __launch_bounds__(256, 2) void gemm_cat_k(
    const float* X, const float* A,
    const float* __restrict__ W, const float* __restrict__ B,
    const int* __restrict__ dga, const int* __restrict__ dgb,
    __half* __restrict__ hs_out, float* out, int N) {
    __shared__ float sW[128 * 64];
    __shared__ float sX[64 * 64];
    __shared__ float sA[64 * 64];
    const int tid = threadIdx.x;

    for (int i = tid; i < 2048; i += 256) ((float4*)sW)[i] = ((const float4*)W)[i];

    const int row0 = blockIdx.x * 64;
    for (int i = tid; i < 1024; i += 256) {
        int r = i >> 4, c4 = (i & 15) << 2;
        int gr = row0 + r;
        float4 xv = make_float4(0.f, 0.f, 0.f, 0.f), av = xv;
        if (gr < N) {
            xv = ((const float4*)X)[(size_t)gr * 16 + (i & 15)];
            av = ((const float4*)A)[(size_t)gr * 16 + (i & 15)];
        }
        int sc = c4 ^ ((r & 12) << 1);
        *(float4*)&sX[(r << 6) + sc] = xv;
        *(float4*)&sA[(r << 6) + sc] = av;
    }
    __syncthreads();

    const int c0 = (tid & 15) << 2;
    const int r0 = (tid >> 4) << 2;
    const int sw = (r0 & 12) << 1;

    float4 bv = *(const float4*)(B + c0);
    float acc[4][4];
#pragma unroll
    for (int i = 0; i < 4; ++i) {
        acc[i][0] = bv.x; acc[i][1] = bv.y; acc[i][2] = bv.z; acc[i][3] = bv.w;
    }

#define GEMM_ROW(i, av)                                                       \
    acc[i][0] = fmaf(av.x, w0.x, acc[i][0]); acc[i][1] = fmaf(av.x, w0.y, acc[i][1]); \
    acc[i][2] = fmaf(av.x, w0.z, acc[i][2]); acc[i][3] = fmaf(av.x, w0.w, acc[i][3]); \
    acc[i][0] = fmaf(av.y, w1.x, acc[i][0]); acc[i][1] = fmaf(av.y, w1.y, acc[i][1]); \
    acc[i][2] = fmaf(av.y, w1.z, acc[i][2]); acc[i][3] = fmaf(av.y, w1.w, acc[i][3]); \
    acc[i][0] = fmaf(av.z, w2.x, acc[i][0]); acc[i][1] = fmaf(av.z, w2.y, acc[i][1]); \
    acc[i][2] = fmaf(av.z, w2.z, acc[i][2]); acc[i][3] = fmaf(av.z, w2.w, acc[i][3]); \
    acc[i][0] = fmaf(av.w, w3.x, acc[i][0]); acc[i][1] = fmaf(av.w, w3.y, acc[i][1]); \
    acc[i][2] = fmaf(av.w, w3.z, acc[i][2]); acc[i][3] = fmaf(av.w, w3.w, acc[i][3]);

#pragma unroll 4
    for (int kb = 0; kb < 64; kb += 4) {
        const int kx = kb ^ sw;
        float4 w0 = *(const float4*)&sW[((kb + 0) << 6) + c0];
        float4 w1 = *(const float4*)&sW[((kb + 1) << 6) + c0];
        float4 w2 = *(const float4*)&sW[((kb + 2) << 6) + c0];
        float4 w3 = *(const float4*)&sW[((kb + 3) << 6) + c0];
        float4 a0 = *(const float4*)&sX[((r0 + 0) << 6) + kx];
        float4 a1 = *(const float4*)&sX[((r0 + 1) << 6) + kx];
        float4 a2 = *(const float4*)&sX[((r0 + 2) << 6) + kx];
        float4 a3 = *(const float4*)&sX[((r0 + 3) << 6) + kx];
        GEMM_ROW(0, a0) GEMM_ROW(1, a1) GEMM_ROW(2, a2) GEMM_ROW(3, a3)
    }
#pragma unroll 4
    for (int kb = 0; kb < 64; kb += 4) {
        const int kx = kb ^ sw;
        float4 w0 = *(const float4*)&sW[((kb + 64) << 6) + c0];
        float4 w1 = *(const float4*)&sW[((kb + 65) << 6) + c0];
        float4 w2 = *(const float4*)&sW[((kb + 66) << 6) + c0];
        float4 w3 = *(const float4*)&sW[((kb + 67) << 6) + c0];
        float4 a0 = *(const float4*)&sA[((r0 + 0) << 6) + kx];
        float4 a1 = *(const float4*)&sA[((r0 + 1) << 6) + kx];
        float4 a2 = *(const float4*)&sA[((r0 + 2) << 6) + kx];
        float4 a3 = *(const float4*)&sA[((r0 + 3) << 6) + kx];
        GEMM_ROW(0, a0) GEMM_ROW(1, a1) GEMM_ROW(2, a2) GEMM_ROW(3, a3)
    }
#undef GEMM_ROW

#pragma unroll
    for (int i = 0; i < 4; ++i) {
        int gr = row0 + r0 + i;
        if (gr < N) {
            float4 o;
            o.x = RELU ? fmaxf(acc[i][0], 0.f) : acc[i][0];
            o.y = RELU ? fmaxf(acc[i][1], 0.f) : acc[i][1];
            o.z = RELU ? fmaxf(acc[i][2], 0.f) : acc[i][2];
            o.w = RELU ? fmaxf(acc[i][3], 0.f) : acc[i][3];
            *(float4*)(out + ((size_t)gr << 6) + c0) = o;
            if (WRITE_HS) {
                int m = dga[gr] + (DEG2 ? dgb[gr] : 0);
                float rr = 1.0f / (float)(m < 1 ? 1 : m);
                __half2 p01 = __floats2half2_rn(o.x * rr, o.y * rr);
                __half2 p23 = __floats2half2_rn(o.z * rr, o.w * rr);
                uint2 u;
                u.x = *(unsigned*)&p01;
                u.y = *(unsigned*)&p23;
                *(uint2*)(hs_out + ((size_t)gr << 6) + c0) = u;
            }
        }
    }
}

extern "C" void kernel_launch(void* const* d_in, const int* in_sizes, int n_in,
                              void* d_out, int out_size, void* d_ws, size_t ws_size,
                              hipStream_t stream) {
    const float* x  = (const float*)d_in[0];
    const int* src  = (const int*)d_in[1];
    const int* dst  = (const int*)d_in[2];
    const float* W1 = (const float*)d_in[3];
    const float* b1 = (const float*)d_in[4];
    const float* W2 = (const float*)d_in[5];
    const float* b2 = (const float*)d_in[6];
    const float* W3 = (const float*)d_in[7];
    const float* b3 = (const float*)d_in[8];

    const int N = in_sizes[0] / 64;
    const int E = in_sizes[1];
    const int NB = (N + BMASK) >> BSHIFT;   // 1024-node buckets (NB <= 128)

    // workspace layout
    float* bufH  = (float*)d_ws;                      // N*64 f32 hidden (h1, h2)
    __half* bufHS = (__half*)(bufH + (size_t)N * 64); // N*64 fp16 pre-scaled feats
    int* deg_out = (int*)(bufHS + (size_t)N * 64);    // N
    int* deg_in  = deg_out + N;                       // N
    int* ip_out  = deg_in + N;                        // N+1
    int* ip_in   = ip_out + (N + 1);                  // N+1
    int* bcnt_out = ip_in + (N + 1);                  // NB
    int* bcnt_in  = bcnt_out + NB;                    // NB
    int* bip_out  = bcnt_in + NB;                     // NB+1
    int* bip_in   = bip_out + (NB + 1);               // NB+1
    int* bcur_out = bip_in + (NB + 1);                // NB
    int* bcur_in  = bcur_out + NB;                    // NB
    unsigned* part_out = (unsigned*)(bcur_in + NB);   // E
    unsigned* part_in  = part_out + E;                // E
    int* col_out = (int*)(part_in + E);               // E
    int* col_in  = col_out + E;                       // E

    float* aggB = (float*)d_out;   // aggregate buffer doubles as output

    const int TPB = 256;
    const int n4  = N * 16;
    const int g4  = (n4 + TPB - 1) / TPB;
    const int gAg = (int)(((size_t)N * 64 + TPB - 1) / TPB);
    const int gGm = (N + 63) / 64;
    const int gP  = (E + PCHUNK - 1) / PCHUNK;
    const int gH  = (E + HCHUNK - 1) / HCHUNK;

    // --- graph build: bucket hist -> scan -> run-reserved partition ->
    //     1024-thread counting sort (emits CSR + degrees) ---
    hipMemsetAsync(bcnt_out, 0, 2 * (size_t)NB * sizeof(int), stream);
    bucket_hist_k<<<gH, TPB, 0, stream>>>(src, dst, bcnt_out, bcnt_in, E);
    bucket_scan_k<<<1, 1024, 0, stream>>>(bcnt_out, bcnt_in, bip_out, bip_in,
                                          bcur_out, bcur_in, NB);
    partition_k<<<gP, TPB, 0, stream>>>(src, dst, bcur_out, bcur_in,
                                        part_out, part_in, E);
    bucket_sort_k<<<dim3(NB, 2), 1024, 0, stream>>>(part_out, bip_out, part_in, bip_in,
                                                    ip_out, ip_in, col_out, col_in,
                                                    deg_out, deg_in, N, E);

    // --- layer 1: 'O' — agg over in-edges of hs0 = fp16(x / outdeg) ---
    scale_rows_k<<<g4, TPB, 0, stream>>>(x, deg_out, bufHS, n4);
    agg_k<<<gAg, TPB, 0, stream>>>(bufHS, ip_in, col_in, aggB, N);
    gemm_cat_k<true, true, false><<<gGm, TPB, 0, stream>>>(x, aggB, W1, b1,
                                                           deg_in, nullptr, bufHS, bufH, N);

    // --- layer 2: 'I' — agg over out-edges of hs1 = fp16(h1 / indeg) ---
    agg_k<<<gAg, TPB, 0, stream>>>(bufHS, ip_out, col_out, aggB, N);
    gemm_cat_k<true, true, true><<<gGm, TPB, 0, stream>>>(bufH, aggB, W2, b2,
                                                          deg_in, deg_out, bufHS, bufH, N);

    // --- layer 3: 'U' — agg both directions of hs2 = fp16(h2 / unddeg) ---
    agg_dual_k<<<gAg, TPB, 0, stream>>>(bufHS, ip_in, col_in, ip_out, col_out, aggB, N);
    gemm_cat_k<false, false, false><<<gGm, TPB, 0, stream>>>(bufH, aggB, W3, b3,
                                                             nullptr, nullptr, nullptr,
                                                             (float*)d_out, N);
}

// Round 12
// 251.701 us; speedup vs baseline: 1.2289x; 1.1678x over previous
//
#include <hip/hip_runtime.h>
#include <hip/hip_fp16.h>

// ---------------------------------------------------------------------------
// 3-layer GraphSAGE (DGL GraphConv norm='left'), N=100k, E=1M, D=H=O=64.
// Round 12 (structure = round 11, GEMM rewritten with MFMA):
//  * gemm: v_mfma_f32_16x16x32_f16, fp32 accumulate. W pre-packed once into
//    fragment-ordered fp16 (prep_w_k) -> B-frags are contiguous 16B L2-hot
//    loads; A-frags read straight from fp32 rows + cvt. No LDS, no barriers.
//    C/D layout per verified mapping: col=lane&15, row=(lane>>4)*4+reg.
//  * agg / build unchanged from round 11 (agg is at its L3 random-gather
//    structural floor: FETCH pinned at 8 XCDs x 12.8MB hs).
// ---------------------------------------------------------------------------

#define BSHIFT 10                 // 1024-node buckets
#define BMASK  ((1 << BSHIFT) - 1)
#define NBMAX  128                // max buckets (N <= 131072)
#define PCHUNK 2048               // edges per partition block
#define HCHUNK 4096               // edges per bucket-hist block

typedef _Float16 half8 __attribute__((ext_vector_type(8)));
typedef float floatx4 __attribute__((ext_vector_type(4)));

// chunked LDS histogram of edges into buckets (both directions)
__global__ __launch_bounds__(256) void bucket_hist_k(
    const int* __restrict__ src, const int* __restrict__ dst,
    int* __restrict__ bcnt_out, int* __restrict__ bcnt_in, int E) {
    __shared__ int h0[NBMAX], h1[NBMAX];
    const int t = threadIdx.x;
    const int e0 = blockIdx.x * HCHUNK;
    int n = E - e0; if (n > HCHUNK) n = HCHUNK;
    for (int i = t; i < NBMAX; i += 256) { h0[i] = 0; h1[i] = 0; }
    __syncthreads();
    for (int i = t; i < n; i += 256) {
        atomicAdd(&h0[src[e0 + i] >> BSHIFT], 1);
        atomicAdd(&h1[dst[e0 + i] >> BSHIFT], 1);
    }
    __syncthreads();
    if (t < NBMAX) {
        int c = h0[t];
        if (c) atomicAdd(&bcnt_out[t], c);
    } else {
        int b = t - NBMAX;
        int c = h1[b];
        if (c) atomicAdd(&bcnt_in[b], c);
    }
}

// single-block scan of bucket counts (NB <= 1024) -> bucket prefix + cursors
__global__ void bucket_scan_k(const int* __restrict__ bcnt_out, const int* __restrict__ bcnt_in,
                              int* __restrict__ bip_out, int* __restrict__ bip_in,
                              int* __restrict__ bcur_out, int* __restrict__ bcur_in, int NB) {
    __shared__ int s[1024];
    int t = threadIdx.x;
#pragma unroll 1
    for (int pass = 0; pass < 2; ++pass) {
        const int* bcnt = pass ? bcnt_in : bcnt_out;
        int* bip = pass ? bip_in : bip_out;
        int* bcur = pass ? bcur_in : bcur_out;
        int v = (t < NB) ? bcnt[t] : 0;
        s[t] = v; __syncthreads();
        for (int off = 1; off < 1024; off <<= 1) {
            int x = (t >= off) ? s[t - off] : 0;
            __syncthreads();
            s[t] += x;
            __syncthreads();
        }
        int excl = s[t] - v;
        if (t < NB) { bip[t] = excl; bcur[t] = excl; }
        if (t == NB) bip[NB] = excl;   // == E
        __syncthreads();
    }
}

// per-block run reservation partition: one contiguous run per (block,bucket),
// so every 64B line of part_* is written by a single XCD (except run edges).
__global__ __launch_bounds__(256) void partition_k(
    const int* __restrict__ src, const int* __restrict__ dst,
    int* __restrict__ bcur_out, int* __restrict__ bcur_in,
    unsigned* __restrict__ part_out, unsigned* __restrict__ part_in, int E) {
    __shared__ int sS[PCHUNK], sD[PCHUNK];
    __shared__ int hist[2][NBMAX];    // counts, then reused as local cursors
    __shared__ int gbase[2][NBMAX];
    const int t = threadIdx.x;
    const int e0 = blockIdx.x * PCHUNK;
    int n = E - e0; if (n > PCHUNK) n = PCHUNK;

    for (int i = t; i < NBMAX; i += 256) { hist[0][i] = 0; hist[1][i] = 0; }
    __syncthreads();
    for (int i = t; i < n; i += 256) {
        int s = src[e0 + i], d = dst[e0 + i];
        sS[i] = s; sD[i] = d;
        atomicAdd(&hist[0][d >> BSHIFT], 1);   // in-partition binned by dst
        atomicAdd(&hist[1][s >> BSHIFT], 1);   // out-partition binned by src
    }
    __syncthreads();
    if (t < NBMAX) {
        int c = hist[0][t];
        gbase[0][t] = c ? atomicAdd(&bcur_in[t], c) : 0;
        hist[0][t] = 0;
    } else {
        int b = t - NBMAX;
        int c = hist[1][b];
        gbase[1][b] = c ? atomicAdd(&bcur_out[b], c) : 0;
        hist[1][b] = 0;
    }
    __syncthreads();
    for (int i = t; i < n; i += 256) {
        int s = sS[i], d = sD[i];
        int bi = d >> BSHIFT;
        int p = gbase[0][bi] + atomicAdd(&hist[0][bi], 1);
        part_in[p] = ((unsigned)s << BSHIFT) | (unsigned)(d & BMASK);
        int bo = s >> BSHIFT;
        int q = gbase[1][bo] + atomicAdd(&hist[1][bo], 1);
        part_out[q] = ((unsigned)d << BSHIFT) | (unsigned)(s & BMASK);
    }
}

// one 1024-thread block per (bucket, direction): counting-sort by local node
// id (1024 bins, 1 bin/thread). Emits ip[], deg[], col[] (byte offsets <<7).
__global__ __launch_bounds__(1024) void bucket_sort_k(
    const unsigned* __restrict__ pa, const int* __restrict__ bipa,
    const unsigned* __restrict__ pb, const int* __restrict__ bipb,
    int* __restrict__ ipa, int* __restrict__ ipb,
    int* __restrict__ cola, int* __restrict__ colb,
    int* __restrict__ dega, int* __restrict__ degb, int N, int E) {
    const unsigned* part = blockIdx.y ? pb : pa;
    const int* bip = blockIdx.y ? bipb : bipa;
    int* ip  = blockIdx.y ? ipb : ipa;
    int* col = blockIdx.y ? colb : cola;
    int* deg = blockIdx.y ? degb : dega;
    __shared__ int cnt[1024];
    __shared__ int s[1024];
    const int g = blockIdx.x, t = threadIdx.x;
    const int b = bip[g], e = bip[g + 1];

    cnt[t] = 0;
    __syncthreads();
    for (int i = b + t; i < e; i += 1024) atomicAdd(&cnt[part[i] & (unsigned)BMASK], 1);
    __syncthreads();

    int v = cnt[t];
    s[t] = v;
    __syncthreads();
    for (int off = 1; off < 1024; off <<= 1) {
        int x = (t >= off) ? s[t - off] : 0;
        __syncthreads();
        s[t] += x;
        __syncthreads();
    }
    int base = b + s[t] - v;                  // exclusive prefix within bucket
    int node = (g << BSHIFT) + t;
    if (node < N) { ip[node] = base; deg[node] = v; }
    cnt[t] = base;                            // becomes the fill cursor
    if (g == 0 && t == 0) ip[N] = E;
    __syncthreads();
    for (int i = b + t; i < e; i += 1024) {
        unsigned rec = part[i];
        int p = atomicAdd(&cnt[rec & (unsigned)BMASK], 1);
        col[p] = (int)((rec >> BSHIFT) << 7); // byte offset of fp16 row
    }
}

// W [128][64] fp32 -> fragment-ordered fp16: wt[((kq*4+ct)*64+l)*8+j] =
// W[kq*32 + (l>>4)*8 + j][ct*16 + (l&15)]. One block per weight matrix.
__global__ void prep_w_k(const float* __restrict__ W1, const float* __restrict__ W2,
                         const float* __restrict__ W3, __half* __restrict__ wt) {
    const float* W = blockIdx.x == 0 ? W1 : (blockIdx.x == 1 ? W2 : W3);
    __half* o = wt + (size_t)blockIdx.x * 8192;
    for (int idx = threadIdx.x; idx < 8192; idx += 256) {
        int j = idx & 7;
        int l = (idx >> 3) & 63;
        int f = idx >> 9;                 // 0..15
        int kq = f >> 2, ct = f & 3;
        int k = (kq << 5) + ((l >> 4) << 3) + j;
        int c = (ct << 4) + (l & 15);
        o[idx] = __float2half(W[k * 64 + c]);
    }
}

// hs[row] = fp16(in[row] / max(deg[row],1)); 4 features per thread (8B store)
__global__ void scale_rows_k(const float* __restrict__ in, const int* __restrict__ deg,
                             __half* __restrict__ out, int n4) {
    int t = blockIdx.x * blockDim.x + threadIdx.x;
    if (t < n4) {
        int m = deg[t >> 4];
        float s = 1.0f / (float)(m < 1 ? 1 : m);
        float4 v = ((const float4*)in)[t];
        __half2 p01 = __floats2half2_rn(v.x * s, v.y * s);
        __half2 p23 = __floats2half2_rn(v.z * s, v.w * s);
        uint2 u;
        u.x = *(unsigned*)&p01;
        u.y = *(unsigned*)&p23;
        *(uint2*)(out + ((size_t)t << 2)) = u;
    }
}

// ---- aggregation (unchanged, round-11 best): one wave per node ----
__device__ __forceinline__ void acc_row(float4& acc, uint2 u) {
    __half2 h01 = *(__half2*)&u.x, h23 = *(__half2*)&u.y;
    acc.x += __low2float(h01); acc.y += __high2float(h01);
    acc.z += __low2float(h23); acc.w += __high2float(h23);
}

__device__ __forceinline__ void agg_list(const char* __restrict__ hsb,
                                         const int* __restrict__ col,
                                         int b, int e, int lane, int grp, int fo8,
                                         float4& a0, float4& a1, float4& a2, float4& a3) {
    for (int base = b; base < e; base += 64) {
        int cnt = e - base; if (cnt > 64) cnt = 64;
        int my = (lane < cnt) ? col[base + lane] : 0;
        for (int j = 0; j < cnt; j += 16) {
            int i0 = j + grp, i1 = j + 4 + grp, i2 = j + 8 + grp, i3 = j + 12 + grp;
            int o0 = __shfl(my, i0 < cnt ? i0 : 0);
            int o1 = __shfl(my, i1 < cnt ? i1 : 0);
            int o2 = __shfl(my, i2 < cnt ? i2 : 0);
            int o3 = __shfl(my, i3 < cnt ? i3 : 0);
            uint2 u0 = *(const uint2*)(hsb + o0 + fo8);
            uint2 u1 = *(const uint2*)(hsb + o1 + fo8);
            uint2 u2 = *(const uint2*)(hsb + o2 + fo8);
            uint2 u3 = *(const uint2*)(hsb + o3 + fo8);
            if (i0 < cnt) acc_row(a0, u0);
            if (i1 < cnt) acc_row(a1, u1);
            if (i2 < cnt) acc_row(a2, u2);
            if (i3 < cnt) acc_row(a3, u3);
        }
    }
}

__device__ __forceinline__ void agg_finish(float4 a0, float4 a1, float4 a2, float4 a3,
                                           float* __restrict__ agg, int node,
                                           int lane, int fo) {
    float4 acc;
    acc.x = (a0.x + a1.x) + (a2.x + a3.x);
    acc.y = (a0.y + a1.y) + (a2.y + a3.y);
    acc.z = (a0.z + a1.z) + (a2.z + a3.z);
    acc.w = (a0.w + a1.w) + (a2.w + a3.w);
    acc.x += __shfl_xor(acc.x, 16); acc.y += __shfl_xor(acc.y, 16);
    acc.z += __shfl_xor(acc.z, 16); acc.w += __shfl_xor(acc.w, 16);
    acc.x += __shfl_xor(acc.x, 32); acc.y += __shfl_xor(acc.y, 32);
    acc.z += __shfl_xor(acc.z, 32); acc.w += __shfl_xor(acc.w, 32);
    if (lane < 16) ((float4*)(agg + ((size_t)node << 6)))[fo] = acc;
}

__global__ void agg_k(const __half* __restrict__ hs, const int* __restrict__ ip,
                      const int* __restrict__ col, float* __restrict__ agg, int N) {
    int node = (blockIdx.x * blockDim.x + threadIdx.x) >> 6;
    int lane = threadIdx.x & 63;
    if (node >= N) return;
    const int grp = lane >> 4, fo = lane & 15, fo8 = fo << 3;
    float4 z = make_float4(0.f, 0.f, 0.f, 0.f);
    float4 a0 = z, a1 = z, a2 = z, a3 = z;
    agg_list((const char*)hs, col, ip[node], ip[node + 1], lane, grp, fo8, a0, a1, a2, a3);
    agg_finish(a0, a1, a2, a3, agg, node, lane, fo);
}

__global__ void agg_dual_k(const __half* __restrict__ hs,
                           const int* __restrict__ ipA, const int* __restrict__ colA,
                           const int* __restrict__ ipB, const int* __restrict__ colB,
                           float* __restrict__ agg, int N) {
    int node = (blockIdx.x * blockDim.x + threadIdx.x) >> 6;
    int lane = threadIdx.x & 63;
    if (node >= N) return;
    const int grp = lane >> 4, fo = lane & 15, fo8 = fo << 3;
    float4 z = make_float4(0.f, 0.f, 0.f, 0.f);
    float4 a0 = z, a1 = z, a2 = z, a3 = z;
    agg_list((const char*)hs, colA, ipA[node], ipA[node + 1], lane, grp, fo8, a0, a1, a2, a3);
    agg_list((const char*)hs, colB, ipB[node], ipB[node + 1], lane, grp, fo8, a0, a1, a2, a3);
    agg_finish(a0, a1, a2, a3, agg, node, lane, fo);
}

// out = [X, A] @ W + B via v_mfma_f32_16x16x32_f16 (fp32 accumulate).
// 256 threads = 4 waves; wave w owns rows [blk*64+w*16, +16). Per wave:
// 4 A-frags (own rows, fp32->fp16 cvt), 16 B-frags (fragment-ordered fp16
// WT, L2-hot), 16 MFMA, epilogue per verified C/D map (col=lane&15,
// row=(lane>>4)*4+reg). No LDS / barriers. X==out aliasing safe: each wave
// loads its A rows before storing them (program order).
template <bool RELU, bool WRITE_HS, bool DEG2>
__global__ __launch_bounds__(256) void gemm_mfma_k(
    const float* X, const float* A, const __half* __restrict__ WT,
    const float* __restrict__ B,
    const int* __restrict__ dga, const int* __restrict__ dgb,
    __half* __restrict__ hs_out, float* out, int N) {
    const int tid = threadIdx.x;
    const int w = tid >> 6, l = tid & 63;
    const int lr = l & 15, lh = l >> 4;
    const int row0 = blockIdx.x * 64 + (w << 4);
    const int arow = row0 + lr;              // A-operand row this lane feeds
    const bool rok = arow < N;

    half8 bf[4][4];
#pragma unroll
    for (int kq = 0; kq < 4; ++kq)
#pragma unroll
        for (int ct = 0; ct < 4; ++ct)
            bf[kq][ct] = *(const half8*)(WT + ((((kq << 2) | ct) << 9) + (l << 3)));

    half8 af[4];
#pragma unroll
    for (int kq = 0; kq < 4; ++kq) {
        const float* src = (kq < 2) ? X : A;
        int kbase = ((kq & 1) << 5) + (lh << 3);
        float4 v0 = make_float4(0.f, 0.f, 0.f, 0.f), v1 = v0;
        if (rok) {
            v0 = *(const float4*)(src + ((size_t)arow << 6) + kbase);
            v1 = *(const float4*)(src + ((size_t)arow << 6) + kbase + 4);
        }
        half8 a;
        a[0] = (_Float16)v0.x; a[1] = (_Float16)v0.y;
        a[2] = (_Float16)v0.z; a[3] = (_Float16)v0.w;
        a[4] = (_Float16)v1.x; a[5] = (_Float16)v1.y;
        a[6] = (_Float16)v1.z; a[7] = (_Float16)v1.w;
        af[kq] = a;
    }

    floatx4 acc[4];
#pragma unroll
    for (int ct = 0; ct < 4; ++ct) {
        float bb = B[(ct << 4) + lr];
        acc[ct][0] = bb; acc[ct][1] = bb; acc[ct][2] = bb; acc[ct][3] = bb;
    }

#pragma unroll
    for (int kq = 0; kq < 4; ++kq)
#pragma unroll
        for (int ct = 0; ct < 4; ++ct)
            acc[ct] = __builtin_amdgcn_mfma_f32_16x16x32_f16(af[kq], bf[kq][ct], acc[ct], 0, 0, 0);

#pragma unroll
    for (int reg = 0; reg < 4; ++reg) {
        int rw = row0 + (lh << 2) + reg;
        if (rw < N) {
            float rr = 1.0f;
            if (WRITE_HS) {
                int m = dga[rw] + (DEG2 ? dgb[rw] : 0);
                rr = 1.0f / (float)(m < 1 ? 1 : m);
            }
#pragma unroll
            for (int ct = 0; ct < 4; ++ct) {
                float v = acc[ct][reg];
                if (RELU) v = fmaxf(v, 0.f);
                out[((size_t)rw << 6) + (ct << 4) + lr] = v;
                if (WRITE_HS)
                    hs_out[((size_t)rw << 6) + (ct << 4) + lr] = __float2half(v * rr);
            }
        }
    }
}

extern "C" void kernel_launch(void* const* d_in, const int* in_sizes, int n_in,
                              void* d_out, int out_size, void* d_ws, size_t ws_size,
                              hipStream_t stream) {
    const float* x  = (const float*)d_in[0];
    const int* src  = (const int*)d_in[1];
    const int* dst  = (const int*)d_in[2];
    const float* W1 = (const float*)d_in[3];
    const float* b1 = (const float*)d_in[4];
    const float* W2 = (const float*)d_in[5];
    const float* b2 = (const float*)d_in[6];
    const float* W3 = (const float*)d_in[7];
    const float* b3 = (const float*)d_in[8];

    const int N = in_sizes[0] / 64;
    const int E = in_sizes[1];
    const int NB = (N + BMASK) >> BSHIFT;   // 1024-node buckets (NB <= 128)

    // workspace layout
    float* bufH  = (float*)d_ws;                      // N*64 f32 hidden (h1, h2)
    __half* bufHS = (__half*)(bufH + (size_t)N * 64); // N*64 fp16 pre-scaled feats
    int* deg_out = (int*)(bufHS + (size_t)N * 64);    // N
    int* deg_in  = deg_out + N;                       // N
    int* ip_out  = deg_in + N;                        // N+1
    int* ip_in   = ip_out + (N + 1);                  // N+1
    int* bcnt_out = ip_in + (N + 1);                  // NB
    int* bcnt_in  = bcnt_out + NB;                    // NB
    int* bip_out  = bcnt_in + NB;                     // NB+1
    int* bip_in   = bip_out + (NB + 1);               // NB+1
    int* bcur_out = bip_in + (NB + 1);                // NB
    int* bcur_in  = bcur_out + NB;                    // NB
    unsigned* part_out = (unsigned*)(bcur_in + NB);   // E
    unsigned* part_in  = part_out + E;                // E
    int* col_out = (int*)(part_in + E);               // E
    int* col_in  = col_out + E;                       // E
    __half* wt = (__half*)(((uintptr_t)(col_in + E) + 255) & ~(uintptr_t)255); // 3*8192

    float* aggB = (float*)d_out;   // aggregate buffer doubles as output

    const int TPB = 256;
    const int n4  = N * 16;
    const int g4  = (n4 + TPB - 1) / TPB;
    const int gAg = (int)(((size_t)N * 64 + TPB - 1) / TPB);
    const int gGm = (N + 63) / 64;
    const int gP  = (E + PCHUNK - 1) / PCHUNK;
    const int gH  = (E + HCHUNK - 1) / HCHUNK;

    // --- graph build + weight prep ---
    hipMemsetAsync(bcnt_out, 0, 2 * (size_t)NB * sizeof(int), stream);
    prep_w_k<<<3, TPB, 0, stream>>>(W1, W2, W3, wt);
    bucket_hist_k<<<gH, TPB, 0, stream>>>(src, dst, bcnt_out, bcnt_in, E);
    bucket_scan_k<<<1, 1024, 0, stream>>>(bcnt_out, bcnt_in, bip_out, bip_in,
                                          bcur_out, bcur_in, NB);
    partition_k<<<gP, TPB, 0, stream>>>(src, dst, bcur_out, bcur_in,
                                        part_out, part_in, E);
    bucket_sort_k<<<dim3(NB, 2), 1024, 0, stream>>>(part_out, bip_out, part_in, bip_in,
                                                    ip_out, ip_in, col_out, col_in,
                                                    deg_out, deg_in, N, E);

    // --- layer 1: 'O' — agg over in-edges of hs0 = fp16(x / outdeg) ---
    scale_rows_k<<<g4, TPB, 0, stream>>>(x, deg_out, bufHS, n4);
    agg_k<<<gAg, TPB, 0, stream>>>(bufHS, ip_in, col_in, aggB, N);
    gemm_mfma_k<true, true, false><<<gGm, TPB, 0, stream>>>(x, aggB, wt, b1,
                                                            deg_in, nullptr, bufHS, bufH, N);

    // --- layer 2: 'I' — agg over out-edges of hs1 = fp16(h1 / indeg) ---
    agg_k<<<gAg, TPB, 0, stream>>>(bufHS, ip_out, col_out, aggB, N);
    gemm_mfma_k<true, true, true><<<gGm, TPB, 0, stream>>>(bufH, aggB, wt + 8192, b2,
                                                           deg_in, deg_out, bufHS, bufH, N);

    // --- layer 3: 'U' — agg both directions of hs2 = fp16(h2 / unddeg) ---
    agg_dual_k<<<gAg, TPB, 0, stream>>>(bufHS, ip_in, col_in, ip_out, col_out, aggB, N);
    gemm_mfma_k<false, false, false><<<gGm, TPB, 0, stream>>>(bufH, aggB, wt + 16384, b3,
                                                              nullptr, nullptr, nullptr,
                                                              (float*)d_out, N);
}